// Round 10
// baseline (134.287 us; speedup 1.0000x reference)
//
#include <hip/hip_runtime.h>

// WL-conv factorized:  out[b,c,n,k] = Y0 + e1[c,k]*Y1 + e2[c,k]*Y2 + e3[c,k]*Y3
// with Ym = M^m labels (M = thresholded adjacency, c-independent) and e_m the
// elementary symmetric polynomials of kernels[c,0..2,k]. Valid because all
// per-step operators (I + k_t ∘ M) commute.
//
// 4 stream-ordered kernels (cooperative launch is rejected on this harness):
//   prep: labels -> swizzled bf16 Y0 (1 MB read, trivial)
//   K1  : block (b,rt) ballot-packs ITS OWN 16 lig rows (256 KB coalesced,
//         4-deep load batches) into 8 KB LDS bits, uses them immediately for
//         Y1 = M Y0 on the matrix pipe, and writes them to global for K2/K3.
//         The 256 MB HBM pack read now overlaps spmm compute.
//   K2  : Y2 = M Y1 (bits from global, R8-proven inner loop)
//   K3  : Y3 = M Y2 + FUSED combine epilogue (y3 in regs; Y1/Y2 read back as
//         swizzled bf16 uint2 — their terms are ~1e-4 of the Y3 term).
// Y chained in MFMA-B-fragment-swizzled bf16:
//   idx(f,s) = (s>>5)*512 + f*32 + ((s>>3)&3)*8 + (s&7)  [u16 units]
// so each wave's B load is one coalesced 1KB segment.
//
// d_out (8 MB): final output only.
// d_ws: bits 8MB | ysw0 | ysw1 | ysw2 (0.5 MB each bf16).

#define BB 4
#define NN 4096
#define KK 16
#define CC 8
#define TT 3
#define WPR (NN / 64)
#define YSWZ (KK * NN)   // u16 elements per batch in swizzled Y (65536)

typedef unsigned long long u64;
typedef unsigned int u32;
typedef unsigned short u16;
typedef __attribute__((ext_vector_type(8))) short s16x8;
typedef __attribute__((ext_vector_type(4))) float f32x4v;

__device__ __forceinline__ u32 bf16_rne(float f) {
    u32 u = __float_as_uint(f);
    return (u + 0x7FFFu + ((u >> 16) & 1u)) >> 16;
}
__device__ __forceinline__ float bf16_f32(u32 h) {
    return __uint_as_float(h << 16);
}

// byte (8 mask bits) -> 8 bf16 {0,1} packed in s16x8 (elem i = bit i)
__device__ __forceinline__ s16x8 expand8(u32 byt) {
    u32 n0 = byt & 0xFu, n1 = (byt >> 4) & 0xFu;
    u32 t0 = (n0 * 0x204081u) & 0x01010101u;   // bytes = bits 0..3
    u32 t1 = (n1 * 0x204081u) & 0x01010101u;   // bytes = bits 4..7
    u32 m0 = (t0 << 7) - t0;                   // bytes 0x7F / 0
    u32 m1 = (t1 << 7) - t1;
    union { u32 w[4]; s16x8 v; } u;
    u.w[0] = __builtin_amdgcn_perm(0u, m0, 0x0C010C00u) << 7;  // b0|b1<<16
    u.w[1] = __builtin_amdgcn_perm(0u, m0, 0x0C030C02u) << 7;  // b2|b3
    u.w[2] = __builtin_amdgcn_perm(0u, m1, 0x0C010C00u) << 7;  // b4|b5
    u.w[3] = __builtin_amdgcn_perm(0u, m1, 0x0C030C02u) << 7;  // b6|b7
    return u.v;
}

// ---------------------------------------------------------------- prep ------
// labels f32 [b][n][f] -> swizzled bf16 Y0
__global__ void prep_kernel(const float* __restrict__ labels,
                            u16* __restrict__ ysw0) {
    int gid = blockIdx.x * 256 + threadIdx.x;            // 32768 tasks
    if (gid >= BB * KK * (NN / 8)) return;
    int n8 = (gid & (NN / 8 - 1)) * 8;
    int f  = (gid >> 9) & (KK - 1);
    int b  = gid >> 13;
    const float* lp = labels + ((long)b * NN + n8) * KK + f;
    union { u16 v[8]; s16x8 s; } o;
#pragma unroll
    for (int i = 0; i < 8; ++i) o.v[i] = (u16)bf16_rne(lp[i * KK]);
    long idx = (long)b * YSWZ + (n8 >> 5) * 512 + f * 32 + ((n8 >> 3) & 3) * 8;
    *(s16x8*)(ysw0 + idx) = o.s;
}

// ----------------------------------------------------------- spmm (MFMA) ----
// grid = BB*(NN/16) = 1024 blocks of 256 threads (4 waves, 4 blocks/CU).
// MODE 0: pack own rows (LDS bits) + spmm, write bits+yout.
// MODE 1: spmm from global bits, write yout.
// MODE 2: spmm from global bits + fused combine epilogue to out.
template<int MODE>
__global__ __launch_bounds__(256, 4)
void spmm_k(const int* __restrict__ lig, const u64* __restrict__ bitsg,
            u64* __restrict__ bitsw, const u16* __restrict__ yin,
            u16* __restrict__ yout, const u16* __restrict__ ysw1,
            const u16* __restrict__ ysw2, const float* __restrict__ labels,
            const float* __restrict__ ker, float* __restrict__ out)
{
    __shared__ float red[3][4][64];
    __shared__ u64 bl[64][16];                   // [word][row-in-tile], 8 KB
    const int bid = blockIdx.x;
    const int rt  = bid & (NN / 16 - 1);
    const int b   = bid >> 8;
    const int tid = threadIdx.x;
    const int lane = tid & 63, ss = tid >> 6;
    const int n16 = lane & 15, g = lane >> 4;
    const int row0 = rt * 16;

    if (MODE == 0) {
        // pack this block's 16 lig rows: 1024 (row,word) tasks, 4-deep batches
        const int* lrow = lig + (long)b * NN * NN + (long)row0 * NN;
        for (int it = 0; it < 256; it += 4) {
            int v[4];
#pragma unroll
            for (int j = 0; j < 4; ++j) {
                int t = (it + j) * 4 + ss;       // wave-interleaved task id
                int row = t >> 6, w = t & 63;
                v[j] = lrow[(long)row * NN + w * 64 + lane];
            }
#pragma unroll
            for (int j = 0; j < 4; ++j) {
                int t = (it + j) * 4 + ss;
                int row = t >> 6, w = t & 63;
                u64 m = __ballot(v[j] >= 1);
                if (lane == 0) {
                    bl[w][row] = m;
                    bitsw[((long)b * WPR + w) * NN + row0 + row] = m;
                }
            }
        }
        __syncthreads();
    }

    // 16 mask words for this wave's s-slice
    u64 wcs[16];
    if (MODE == 0) {
#pragma unroll
        for (int wi = 0; wi < 16; ++wi) wcs[wi] = bl[ss * 16 + wi][n16];
    } else {
        const u64* bb = bitsg + ((long)b * WPR + ss * 16) * NN + row0 + n16;
#pragma unroll
        for (int wi = 0; wi < 16; ++wi) wcs[wi] = bb[(long)wi * NN];
    }

    // swizzled B: word w fragment base = w*1024 + n16*32 + g*8 (b1 at +512)
    const u16* yb = yin + (long)b * YSWZ + (ss * 16) * 1024 + n16 * 32 + g * 8;
    f32x4v accA = {0.f, 0.f, 0.f, 0.f}, accB = {0.f, 0.f, 0.f, 0.f};
#pragma unroll
    for (int wi = 0; wi < 16; ++wi) {
        u64 h = wcs[wi] >> (g * 8);
        u32 lo8 = (u32)h & 0xFFu;
        u32 hi8 = ((u32)(h >> 32)) & 0xFFu;
        const u16* yr = yb + wi * 1024;
        s16x8 b0 = *(const s16x8*)(yr);
        s16x8 b1 = *(const s16x8*)(yr + 512);
        accA = __builtin_amdgcn_mfma_f32_16x16x32_bf16(expand8(lo8), b0, accA, 0, 0, 0);
        accB = __builtin_amdgcn_mfma_f32_16x16x32_bf16(expand8(hi8), b1, accB, 0, 0, 0);
    }

    f32x4v acc;
#pragma unroll
    for (int r = 0; r < 4; ++r) acc[r] = accA[r] + accB[r];

    if (ss != 0) {
#pragma unroll
        for (int r = 0; r < 4; ++r) red[ss - 1][r][lane] = acc[r];
    }
    __syncthreads();
    if (ss == 0) {
#pragma unroll
        for (int r = 0; r < 4; ++r)
            acc[r] += red[0][r][lane] + red[1][r][lane] + red[2][r][lane];

        // D: col = n16 (feature), row-in-tile = 4g+r  (m89-verified layout)
        const int s0 = row0 + 4 * g;
        const long idx = (long)b * YSWZ + (s0 >> 5) * 512 + n16 * 32 +
                         ((s0 >> 3) & 3) * 8 + (s0 & 7);
        if (MODE < 2) {
            u32 q0 = bf16_rne(acc[0]) | (bf16_rne(acc[1]) << 16);
            u32 q1 = bf16_rne(acc[2]) | (bf16_rne(acc[3]) << 16);
            *(uint2*)(yout + idx) = make_uint2(q0, q1);
        } else {
            // fused combine: acc = Y3 tile; read back Y1,Y2 (swizzled bf16)
            float e1v[CC], e2v[CC], e3v[CC];
#pragma unroll
            for (int c = 0; c < CC; ++c) {
                float a = ker[(c * TT + 0) * KK + n16];
                float d = ker[(c * TT + 1) * KK + n16];
                float e = ker[(c * TT + 2) * KK + n16];
                e1v[c] = a + d + e;
                e2v[c] = a * d + a * e + d * e;
                e3v[c] = a * d * e;
            }
            uint2 u1 = *(const uint2*)(ysw1 + idx);
            uint2 u2 = *(const uint2*)(ysw2 + idx);
            float y1v[4] = { bf16_f32(u1.x & 0xFFFFu), bf16_f32(u1.x >> 16),
                             bf16_f32(u1.y & 0xFFFFu), bf16_f32(u1.y >> 16) };
            float y2v[4] = { bf16_f32(u2.x & 0xFFFFu), bf16_f32(u2.x >> 16),
                             bf16_f32(u2.y & 0xFFFFu), bf16_f32(u2.y >> 16) };
#pragma unroll
            for (int r = 0; r < 4; ++r) {
                int row = row0 + 4 * g + r;
                float y0 = labels[((long)b * NN + row) * KK + n16];
#pragma unroll
                for (int c = 0; c < CC; ++c)
                    out[(((long)b * CC + c) * NN + row) * KK + n16] =
                        y0 + e1v[c] * y1v[r] + e2v[c] * y2v[r] + e3v[c] * acc[r];
            }
        }
    }
}

// --------------------------------------------------------------- launch -----
extern "C" void kernel_launch(void* const* d_in, const int* in_sizes, int n_in,
                              void* d_out, int out_size, void* d_ws, size_t ws_size,
                              hipStream_t stream) {
    const float* labels = (const float*)d_in[0];   // [B,N,K] f32
    const int*   lig    = (const int*)d_in[1];     // [B,N,N] i32
    const float* ker    = (const float*)d_in[2];   // [C,T,K] f32
    float* out = (float*)d_out;

    u64* bits = (u64*)d_ws;                        // 8 MB
    u16* ysw0 = (u16*)((char*)d_ws + (long)BB * WPR * NN * 8);
    u16* ysw1 = ysw0 + (long)BB * YSWZ;
    u16* ysw2 = ysw1 + (long)BB * YSWZ;

    hipLaunchKernelGGL(prep_kernel, dim3(128), dim3(256), 0, stream,
                       labels, ysw0);

    dim3 sgrid(BB * (NN / 16));                    // 1024 blocks
    hipLaunchKernelGGL((spmm_k<0>), sgrid, dim3(256), 0, stream,
                       lig, (const u64*)nullptr, bits, ysw0, ysw1,
                       (const u16*)nullptr, (const u16*)nullptr,
                       (const float*)nullptr, (const float*)nullptr,
                       (float*)nullptr);
    hipLaunchKernelGGL((spmm_k<1>), sgrid, dim3(256), 0, stream,
                       (const int*)nullptr, (const u64*)bits, (u64*)nullptr,
                       ysw1, ysw2, (const u16*)nullptr, (const u16*)nullptr,
                       (const float*)nullptr, (const float*)nullptr,
                       (float*)nullptr);
    hipLaunchKernelGGL((spmm_k<2>), sgrid, dim3(256), 0, stream,
                       (const int*)nullptr, (const u64*)bits, (u64*)nullptr,
                       ysw2, (u16*)nullptr, (const u16*)ysw1, (const u16*)ysw2,
                       labels, ker, out);
}

// Round 11
// 95.597 us; speedup vs baseline: 1.4047x; 1.4047x over previous
//
#include <hip/hip_runtime.h>

// WL-conv factorized:  out[b,c,n,k] = Y0 + e1[c,k]*Y1 + e2[c,k]*Y2 + e3[c,k]*Y3
// with Ym = M^m labels (M = thresholded adjacency, c-independent) and e_m the
// elementary symmetric polynomials of kernels[c,0..2,k]. Valid because all
// per-step operators (I + k_t ∘ M) commute.
//
// Kernels (stream-ordered):
//   pack : int4 (16B/lane) lig read -> 4 ballots/iter -> bit-words; prep
//          (labels -> swizzled bf16 Y0) fused in. Standalone streaming pack
//          proved faster than fused-into-spmm (R10: +7us).
//   K1/K2: Y_{m+1} = M Y_m on matrix pipe; masks preloaded (16 u64), B
//          fragments via explicit depth-4 register pipeline; no atomics.
//   K3   : last pass + fused combine epilogue (Y1/Y2 read back as bf16).
//
// int4 ballots permute element order; the permutation is baked into the Y
// layout via ypos(f,s) so the spmm READER is unchanged:
//   ballot word w' = 4*(s>>8) + (s&3), bit l = (s>>2)&63
//   ypos(f,s) = (s>>8)*4096 + (s&3)*1024 + ((s>>7)&1)*512
//             + f*32 + ((s>>5)&3)*8 + ((s>>2)&7)          [u16 units]
//
// d_out (8 MB): final output only.
// d_ws: bits 8MB | ysw0 | ysw1 | ysw2 (0.5 MB each, swizzled bf16).

#define BB 4
#define NN 4096
#define KK 16
#define CC 8
#define TT 3
#define WPR (NN / 64)
#define YSWZ (KK * NN)   // u16 elements per batch in swizzled Y (65536)

typedef unsigned long long u64;
typedef unsigned int u32;
typedef unsigned short u16;
typedef __attribute__((ext_vector_type(8))) short s16x8;
typedef __attribute__((ext_vector_type(4))) float f32x4v;

__device__ __forceinline__ u32 bf16_rne(float f) {
    u32 u = __float_as_uint(f);
    return (u + 0x7FFFu + ((u >> 16) & 1u)) >> 16;
}
__device__ __forceinline__ float bf16_f32(u32 h) {
    return __uint_as_float(h << 16);
}
__device__ __forceinline__ long ypos(int f, int s) {
    return ((long)(s >> 8) << 12) + (s & 3) * 1024 + ((s >> 7) & 1) * 512 +
           f * 32 + ((s >> 5) & 3) * 8 + ((s >> 2) & 7);
}

// byte (8 mask bits) -> 8 bf16 {0,1} packed in s16x8 (elem i = bit i)
__device__ __forceinline__ s16x8 expand8(u32 byt) {
    u32 n0 = byt & 0xFu, n1 = (byt >> 4) & 0xFu;
    u32 t0 = (n0 * 0x204081u) & 0x01010101u;
    u32 t1 = (n1 * 0x204081u) & 0x01010101u;
    u32 m0 = (t0 << 7) - t0;
    u32 m1 = (t1 << 7) - t1;
    union { u32 w[4]; s16x8 v; } u;
    u.w[0] = __builtin_amdgcn_perm(0u, m0, 0x0C010C00u) << 7;
    u.w[1] = __builtin_amdgcn_perm(0u, m0, 0x0C030C02u) << 7;
    u.w[2] = __builtin_amdgcn_perm(0u, m1, 0x0C010C00u) << 7;
    u.w[3] = __builtin_amdgcn_perm(0u, m1, 0x0C030C02u) << 7;
    return u.v;
}

// ---------------------------------------------------------------- pack ------
__global__ __launch_bounds__(256)
void pack_kernel(const int* __restrict__ lig, u64* __restrict__ bits,
                 const float* __restrict__ labels, u16* __restrict__ ysw0) {
    int gid = blockIdx.x * 256 + threadIdx.x;
    if (gid < BB * KK * (NN / 4)) {                      // 65536 prep tasks
        int s4 = (gid & (NN / 4 - 1)) * 4;
        int f  = (gid >> 10) & (KK - 1);
        int b  = gid >> 14;
        long base = (long)b * YSWZ + ypos(f, s4);        // s4 mult of 4: +j*1024
        const float* lp = labels + ((long)b * NN + s4) * KK + f;
#pragma unroll
        for (int j = 0; j < 4; ++j)
            ysw0[base + j * 1024] = (u16)bf16_rne(lp[j * KK]);
    }
    const long total = (long)BB * (WPR / 4) * NN;        // 262,144 int4-groups
    long wid  = ((long)gid) >> 6;
    int  lane = threadIdx.x & 63;
    long nw   = ((long)gridDim.x * 256) >> 6;
    for (long o = wid; o < total; o += nw) {
        int n  = (int)(o & (NN - 1));
        int w4 = (int)((o >> 12) & (WPR / 4 - 1));
        int b  = (int)(o >> 16);
        int4 v = *(const int4*)(lig + ((long)b * NN + n) * NN + w4 * 256 + lane * 4);
        u64 m0 = __ballot(v.x >= 1);
        u64 m1 = __ballot(v.y >= 1);
        u64 m2 = __ballot(v.z >= 1);
        u64 m3 = __ballot(v.w >= 1);
        if (lane == 0) {
            u64* bw = bits + ((long)b * WPR + 4 * w4) * NN + n;
            bw[0] = m0; bw[NN] = m1; bw[2 * NN] = m2; bw[3 * NN] = m3;
        }
    }
}

// ----------------------------------------------------------- spmm (MFMA) ----
// grid = BB*(NN/16) = 1024 blocks of 256 threads (4 waves, 4 blocks/CU).
// Wave ss: rows row0..row0+15 x words [ss*16, ss*16+16). Masks preloaded;
// B fragments depth-4 register-pipelined. LAST: fused combine epilogue.
template<bool LAST>
__global__ __launch_bounds__(256, 4)
void spmm_k(const u64* __restrict__ bits, const u16* __restrict__ yin,
            u16* __restrict__ yout, const u16* __restrict__ ysw1,
            const u16* __restrict__ ysw2, const float* __restrict__ labels,
            const float* __restrict__ ker, float* __restrict__ out)
{
    __shared__ float red[3][4][64];
    const int bid = blockIdx.x;
    const int rt  = bid & (NN / 16 - 1);
    const int b   = bid >> 8;
    const int tid = threadIdx.x;
    const int lane = tid & 63, ss = tid >> 6;
    const int n16 = lane & 15, g = lane >> 4;
    const int row0 = rt * 16;

    // masks first (deepest latency), then B pipeline
    const u64* bb = bits + ((long)b * WPR + ss * 16) * NN + row0 + n16;
    u64 wcs[16];
#pragma unroll
    for (int wi = 0; wi < 16; ++wi) wcs[wi] = bb[(long)wi * NN];

    const u16* yb = yin + (long)b * YSWZ + (ss * 16) * 1024 + n16 * 32 + g * 8;
    s16x8 p0[4], p1[4];
#pragma unroll
    for (int i = 0; i < 4; ++i) {
        p0[i] = *(const s16x8*)(yb + i * 1024);
        p1[i] = *(const s16x8*)(yb + i * 1024 + 512);
    }

    f32x4v accA = {0.f, 0.f, 0.f, 0.f}, accB = {0.f, 0.f, 0.f, 0.f};
#pragma unroll
    for (int wi = 0; wi < 16; ++wi) {
        const int slot = wi & 3;
        s16x8 b0 = p0[slot], b1 = p1[slot];
        if (wi + 4 < 16) {
            p0[slot] = *(const s16x8*)(yb + (wi + 4) * 1024);
            p1[slot] = *(const s16x8*)(yb + (wi + 4) * 1024 + 512);
        }
        u64 h = wcs[wi] >> (g * 8);
        u32 lo8 = (u32)h & 0xFFu;
        u32 hi8 = ((u32)(h >> 32)) & 0xFFu;
        accA = __builtin_amdgcn_mfma_f32_16x16x32_bf16(expand8(lo8), b0, accA, 0, 0, 0);
        accB = __builtin_amdgcn_mfma_f32_16x16x32_bf16(expand8(hi8), b1, accB, 0, 0, 0);
    }

    f32x4v acc;
#pragma unroll
    for (int r = 0; r < 4; ++r) acc[r] = accA[r] + accB[r];

    if (ss != 0) {
#pragma unroll
        for (int r = 0; r < 4; ++r) red[ss - 1][r][lane] = acc[r];
    }
    __syncthreads();
    if (ss == 0) {
#pragma unroll
        for (int r = 0; r < 4; ++r)
            acc[r] += red[0][r][lane] + red[1][r][lane] + red[2][r][lane];

        // D: col = n16 (feature), row-in-tile = 4g+r; rows = next pass's s
        const int s0 = row0 + 4 * g;                     // mult of 4: +r*1024
        const long base = (long)b * YSWZ + ypos(n16, s0);
        if (!LAST) {
#pragma unroll
            for (int r = 0; r < 4; ++r)
                yout[base + r * 1024] = (u16)bf16_rne(acc[r]);
        } else {
            float e1v[CC], e2v[CC], e3v[CC];
#pragma unroll
            for (int c = 0; c < CC; ++c) {
                float a = ker[(c * TT + 0) * KK + n16];
                float d = ker[(c * TT + 1) * KK + n16];
                float e = ker[(c * TT + 2) * KK + n16];
                e1v[c] = a + d + e;
                e2v[c] = a * d + a * e + d * e;
                e3v[c] = a * d * e;
            }
            float y1v[4], y2v[4];
#pragma unroll
            for (int r = 0; r < 4; ++r) {
                y1v[r] = bf16_f32(ysw1[base + r * 1024]);
                y2v[r] = bf16_f32(ysw2[base + r * 1024]);
            }
#pragma unroll
            for (int r = 0; r < 4; ++r) {
                int row = s0 + r;
                float y0 = labels[((long)b * NN + row) * KK + n16];
#pragma unroll
                for (int c = 0; c < CC; ++c)
                    out[(((long)b * CC + c) * NN + row) * KK + n16] =
                        y0 + e1v[c] * y1v[r] + e2v[c] * y2v[r] + e3v[c] * acc[r];
            }
        }
    }
}

// --------------------------------------------------------------- launch -----
extern "C" void kernel_launch(void* const* d_in, const int* in_sizes, int n_in,
                              void* d_out, int out_size, void* d_ws, size_t ws_size,
                              hipStream_t stream) {
    const float* labels = (const float*)d_in[0];   // [B,N,K] f32
    const int*   lig    = (const int*)d_in[1];     // [B,N,N] i32
    const float* ker    = (const float*)d_in[2];   // [C,T,K] f32
    float* out = (float*)d_out;

    u64* bits = (u64*)d_ws;                        // 8 MB
    u16* ysw0 = (u16*)((char*)d_ws + (long)BB * WPR * NN * 8);
    u16* ysw1 = ysw0 + (long)BB * YSWZ;
    u16* ysw2 = ysw1 + (long)BB * YSWZ;

    hipLaunchKernelGGL(pack_kernel, dim3(2048), dim3(256), 0, stream,
                       lig, bits, labels, ysw0);

    dim3 sgrid(BB * (NN / 16));                    // 1024 blocks
    hipLaunchKernelGGL((spmm_k<false>), sgrid, dim3(256), 0, stream,
                       bits, ysw0, ysw1, (const u16*)nullptr, (const u16*)nullptr,
                       (const float*)nullptr, (const float*)nullptr,
                       (float*)nullptr);
    hipLaunchKernelGGL((spmm_k<false>), sgrid, dim3(256), 0, stream,
                       bits, ysw1, ysw2, (const u16*)nullptr, (const u16*)nullptr,
                       (const float*)nullptr, (const float*)nullptr,
                       (float*)nullptr);
    hipLaunchKernelGGL((spmm_k<true>),  sgrid, dim3(256), 0, stream,
                       bits, ysw2, (u16*)nullptr, ysw1, ysw2,
                       labels, ker, out);
}